// Round 5
// baseline (48.883 us; speedup 1.0000x reference)
//
#include <hip/hip_runtime.h>
#include <math.h>

#define B_ 8
#define U_ 512
#define T_ 1024
#define H_ 512
#define D_ 128
#define K_ 10

#define UT 8      // u rows per attend block / scan tile size
#define TC 64     // t chunk size
#define NTILES 64 // U_/UT

// ---------------- Kernel A: params + tile-local kappa scans -----------------
// Grid 256 blocks x 512 threads (8 waves). Wave w handles rows {2w, 2w+1} of
// the block's 16 rows: lane half = row, lane j = output column (j<30 active).
// Both halves read identical W addresses -> TA dedups -> W L2 traffic halves
// vs 1 row/wave. 2048 waves = 8 waves/CU = 2/SIMD for latency hiding.
__global__ __launch_bounds__(512)
void prep_kernel(const float* __restrict__ h_t,
                 const float* __restrict__ W,
                 const float* __restrict__ bias,
                 float* __restrict__ alpha,
                 float* __restrict__ beta,
                 float* __restrict__ L,     // [B*U][K] tile-local inclusive sums
                 float* __restrict__ T) {   // [B][NTILES][K] tile totals
    __shared__ float kin_s[16][K_];

    int tid = threadIdx.x;
    int lane = tid & 63;
    int w = tid >> 6;                   // 0..7
    int half = lane >> 5;               // row select within wave
    int j = lane & 31;                  // output column, active j<30
    int rloc = 2 * w + half;            // 0..15
    int row = blockIdx.x * 16 + rloc;   // 0..4095

    const float4* h4 = (const float4*)(h_t + (size_t)row * H_);
    int jj = (j < 30) ? j : 0;          // pad lanes read a safe column
    float acc = 0.f;
    #pragma unroll 8
    for (int i4 = 0; i4 < H_ / 4; ++i4) {
        float4 hv = h4[i4];             // per-half broadcast (16B x 2 rows)
        const float* wp = W + (size_t)(4 * i4) * (3 * K_) + jj;
        acc += hv.x * wp[0] + hv.y * wp[30] + hv.z * wp[60] + hv.w * wp[90];
    }
    if (j < 30) {
        float p = __expf(acc + bias[j]);
        size_t base = (size_t)row * K_;
        if (j < 10)       alpha[base + j] = p;
        else if (j < 20)  beta[base + (j - 10)] = p;
        else              kin_s[rloc][j - 20] = 0.2f * p;
    }
    __syncthreads();

    // tile-local inclusive scans over the block's two 8-row tiles
    if (tid < 16 * K_) {
        int u_l = tid / K_;             // 0..15
        int k = tid % K_;               // 0..9
        int tb = u_l & ~(UT - 1);       // tile base within block
        float s = 0.f;
        for (int r = tb; r <= u_l; ++r) s += kin_s[r][k];
        int urow = blockIdx.x * 16 + u_l;
        L[(size_t)urow * K_ + k] = s;
        if ((u_l & (UT - 1)) == (UT - 1)) {
            int b = urow >> 9;                  // /U_
            int tile = (urow & (U_ - 1)) >> 3;  // /UT
            T[((size_t)b * NTILES + tile) * K_ + k] = s;
        }
    }
}

// ---------------- Kernel B: prefix combine + phi + masked matmul ------------
// Grid 512 blocks (64 tiles x 8 batches) x 256 threads. (unchanged from R4)
__global__ __launch_bounds__(256)
void attend_kernel(const float* __restrict__ alpha,
                   const float* __restrict__ beta,
                   const float* __restrict__ L,
                   const float* __restrict__ T,
                   const float* __restrict__ ctx,
                   const float* __restrict__ mask,
                   float* __restrict__ out) {
    __shared__ float a_s[UT][K_], b_s[UT][K_], k_s[UT][K_];
    __shared__ float phi_s[UT][68];          // row stride 272B (16B-aligned)
    __shared__ float ctx_s[TC][D_];          // 32 KB
    __shared__ float red_lo[256], red_hi[256];

    int tid = threadIdx.x;
    int b = blockIdx.x >> 6;
    int mytile = blockIdx.x & 63;
    int u0 = mytile * UT;

    // header: reconstruct kappa = sum of preceding tile totals + local scan
    float lo = 1e30f, hi = -1e30f;
    if (tid < UT * K_) {
        int u_l = tid / K_, k = tid % K_;
        size_t idx = ((size_t)(b * U_) + u0 + u_l) * K_ + k;
        float pre = 0.f;
        const float* tp = T + ((size_t)b * NTILES) * K_ + k;
        for (int jt = 0; jt < mytile; ++jt) pre += tp[(size_t)jt * K_];
        float kv = pre + L[idx];
        float av = alpha[idx], bvv = beta[idx];
        a_s[u_l][k] = av; b_s[u_l][k] = bvv; k_s[u_l][k] = kv;
        float r = sqrtf(88.f / bvv);   // f32 exp underflow radius
        lo = kv - r; hi = kv + r;
    }
    red_lo[tid] = lo; red_hi[tid] = hi;
    __syncthreads();
    for (int s = 128; s > 0; s >>= 1) {
        if (tid < s) {
            red_lo[tid] = fminf(red_lo[tid], red_lo[tid + s]);
            red_hi[tid] = fmaxf(red_hi[tid], red_hi[tid + s]);
        }
        __syncthreads();
    }
    int t_begin = max(0, (int)floorf(red_lo[0]));
    int t_end   = min(T_, (int)ceilf(red_hi[0]) + 1);
    t_begin = (t_begin / TC) * TC;

    int u_l = tid >> 5;                  // 0..7
    int g   = tid & 31;                  // d block: 4g..4g+3
    float acc[4];
    #pragma unroll
    for (int i = 0; i < 4; ++i) acc[i] = 0.f;

    for (int t0 = t_begin; t0 < t_end; t0 += TC) {
        __syncthreads();
        // stage ctx chunk (coalesced float4)
        {
            const float4* src = (const float4*)(ctx + (((size_t)b * T_ + t0) * D_));
            float4* dst = (float4*)(&ctx_s[0][0]);
            #pragma unroll
            for (int i = 0; i < (TC * D_ / 4) / 256; ++i)
                dst[tid + 256 * i] = src[tid + 256 * i];
        }
        // phi: UT*TC = 512 values, 2 per thread
        #pragma unroll
        for (int i = 0; i < 2; ++i) {
            int lin = tid + 256 * i;
            int uu = lin >> 6;           // wave-uniform -> broadcast param reads
            int tl = lin & 63;
            float tf = (float)(t0 + tl);
            float ph = 0.f;
            #pragma unroll
            for (int k = 0; k < K_; ++k) {
                float d = k_s[uu][k] - tf;
                float x = b_s[uu][k] * d * d;
                ph += a_s[uu][k] * __expf(-x);
            }
            phi_s[uu][tl] = ph * mask[(size_t)b * T_ + t0 + tl];
        }
        __syncthreads();
        // acc += phi * ctx   (phi hoisted 4-wide)
        for (int tl4 = 0; tl4 < TC / 4; ++tl4) {
            float4 ph4 = *(const float4*)(&phi_s[u_l][4 * tl4]);
            #pragma unroll
            for (int q = 0; q < 4; ++q) {
                float ph = (q == 0) ? ph4.x : (q == 1) ? ph4.y : (q == 2) ? ph4.z : ph4.w;
                float4 c0 = ((const float4*)(&ctx_s[4 * tl4 + q][0]))[g];
                acc[0] += ph * c0.x; acc[1] += ph * c0.y;
                acc[2] += ph * c0.z; acc[3] += ph * c0.w;
            }
        }
    }

    float* orow = out + ((size_t)b * U_ + u0 + u_l) * D_;
    *(float4*)(orow + 4 * g) = make_float4(acc[0], acc[1], acc[2], acc[3]);
}

extern "C" void kernel_launch(void* const* d_in, const int* in_sizes, int n_in,
                              void* d_out, int out_size, void* d_ws, size_t ws_size,
                              hipStream_t stream) {
    const float* h_t  = (const float*)d_in[0];
    const float* ctx  = (const float*)d_in[1];
    const float* mask = (const float*)d_in[2];
    const float* W    = (const float*)d_in[3];
    const float* bias = (const float*)d_in[4];
    float* out = (float*)d_out;

    const size_t NPARAM = (size_t)B_ * U_ * K_;       // 40960
    float* alpha = (float*)d_ws;
    float* beta  = alpha + NPARAM;
    float* L     = beta + NPARAM;
    float* T     = L + NPARAM;                        // B*NTILES*K = 5120

    prep_kernel<<<dim3(256), dim3(512), 0, stream>>>(h_t, W, bias, alpha, beta, L, T);
    attend_kernel<<<dim3(512), dim3(256), 0, stream>>>(alpha, beta, L, T, ctx, mask, out);
}

// Round 6
// 36.266 us; speedup vs baseline: 1.3479x; 1.3479x over previous
//
#include <hip/hip_runtime.h>
#include <math.h>

#define B_ 8
#define U_ 512
#define T_ 1024
#define H_ 512
#define D_ 128
#define K_ 10

#define UT 8      // u rows per attend block / scan tile size
#define TC 32     // t chunk size
#define NTILES 64 // U_/UT

// ---------------- Kernel A: params (split-H) + tile-local kappa scan --------
// Grid 512 blocks x 512 threads = 4096 waves (16/CU, 4/SIMD).
// Block = 8 rows (one UT tile). Wave w: row-pair q=w>>1, H-half hs=w&1.
// Lane: j=lane&31 (col, <30 active), s=lane>>5 (row within pair).
// Each wave streams 30KB of W (half) for 2 rows -> 122 MB L2 total.
// Partial dots combined across H-halves in LDS, then exp + tile scan.
__global__ __launch_bounds__(512)
void prep_kernel(const float* __restrict__ h_t,
                 const float* __restrict__ W,
                 const float* __restrict__ bias,
                 float* __restrict__ alpha,
                 float* __restrict__ beta,
                 float* __restrict__ L,     // [B*U][K] tile-local inclusive sums
                 float* __restrict__ T) {   // [B][NTILES][K] tile totals
    __shared__ float part_s[8][30][2];
    __shared__ float kin_s[8][K_];

    int tid = threadIdx.x;
    int lane = tid & 63;
    int w = tid >> 6;               // 0..7
    int q = w >> 1;                 // row-pair 0..3
    int hs = w & 1;                 // H-half 0/1
    int j = lane & 31;              // col (j<30 active)
    int s = lane >> 5;              // row within pair
    int rloc = q * 2 + s;           // 0..7
    int row = blockIdx.x * 8 + rloc;
    int jj = (j < 30) ? j : 29;

    const float4* hp = (const float4*)(h_t + (size_t)row * H_ + hs * (H_ / 2));
    const float* wp0 = W + (size_t)(hs * (H_ / 2)) * (3 * K_) + jj;
    float acc = 0.f;
    #pragma unroll 8
    for (int i4 = 0; i4 < (H_ / 2) / 4; ++i4) {
        float4 h4 = hp[i4];                         // uniform per 32-half -> TA dedup
        const float* wp = wp0 + (size_t)(4 * i4) * (3 * K_);
        acc += h4.x * wp[0] + h4.y * wp[30] + h4.z * wp[60] + h4.w * wp[90];
    }
    if (j < 30) part_s[rloc][j][hs] = acc;
    __syncthreads();

    // combine halves, exp, route
    if (tid < 240) {
        int r = tid / 30, c = tid % 30;
        float p = __expf(part_s[r][c][0] + part_s[r][c][1] + bias[c]);
        int row2 = blockIdx.x * 8 + r;
        if (c < 10)      alpha[(size_t)row2 * K_ + c] = p;
        else if (c < 20) beta[(size_t)row2 * K_ + (c - 10)] = p;
        else             kin_s[r][c - 20] = 0.2f * p;
    }
    __syncthreads();

    // tile-local inclusive scan (block = exactly one 8-row tile)
    if (tid < UT * K_) {
        int u_l = tid / K_, k = tid % K_;
        float ssum = 0.f;
        for (int r = 0; r <= u_l; ++r) ssum += kin_s[r][k];
        int urow = blockIdx.x * 8 + u_l;
        L[(size_t)urow * K_ + k] = ssum;
        if (u_l == UT - 1) {
            int b = urow >> 9;                  // /U_
            int tile = (urow & (U_ - 1)) >> 3;  // /UT
            T[((size_t)b * NTILES + tile) * K_ + k] = ssum;
        }
    }
}

// ---------------- Kernel B: prefix combine + phi + masked matmul ------------
// Grid 512 blocks (64 tiles x 8 batches) x 256 threads. TC=32 tightens the
// active-window coverage (~50 t-cols avg vs ~109 at TC=64).
__global__ __launch_bounds__(256)
void attend_kernel(const float* __restrict__ alpha,
                   const float* __restrict__ beta,
                   const float* __restrict__ L,
                   const float* __restrict__ T,
                   const float* __restrict__ ctx,
                   const float* __restrict__ mask,
                   float* __restrict__ out) {
    __shared__ float a_s[UT][K_], b_s[UT][K_], k_s[UT][K_];
    __shared__ float phi_s[UT][TC + 4];      // stride 144B (16B-aligned)
    __shared__ float ctx_s[TC][D_];          // 16 KB
    __shared__ float red_lo[256], red_hi[256];

    int tid = threadIdx.x;
    int b = blockIdx.x >> 6;
    int mytile = blockIdx.x & 63;
    int u0 = mytile * UT;

    // header: reconstruct kappa = sum of preceding tile totals + local scan
    float lo = 1e30f, hi = -1e30f;
    if (tid < UT * K_) {
        int u_l = tid / K_, k = tid % K_;
        size_t idx = ((size_t)(b * U_) + u0 + u_l) * K_ + k;
        float pre = 0.f;
        const float* tp = T + ((size_t)b * NTILES) * K_ + k;
        for (int jt = 0; jt < mytile; ++jt) pre += tp[(size_t)jt * K_];
        float kv = pre + L[idx];
        float av = alpha[idx], bvv = beta[idx];
        a_s[u_l][k] = av; b_s[u_l][k] = bvv; k_s[u_l][k] = kv;
        float r = sqrtf(88.f / bvv);   // f32 exp underflow radius
        lo = kv - r; hi = kv + r;
    }
    red_lo[tid] = lo; red_hi[tid] = hi;
    __syncthreads();
    for (int s = 128; s > 0; s >>= 1) {
        if (tid < s) {
            red_lo[tid] = fminf(red_lo[tid], red_lo[tid + s]);
            red_hi[tid] = fmaxf(red_hi[tid], red_hi[tid + s]);
        }
        __syncthreads();
    }
    int t_begin = max(0, (int)floorf(red_lo[0]));
    int t_end   = min(T_, (int)ceilf(red_hi[0]) + 1);
    t_begin = (t_begin / TC) * TC;

    int u_l = tid >> 5;                  // 0..7
    int g   = tid & 31;                  // d block: 4g..4g+3
    float acc[4];
    #pragma unroll
    for (int i = 0; i < 4; ++i) acc[i] = 0.f;

    for (int t0 = t_begin; t0 < t_end; t0 += TC) {
        __syncthreads();
        // stage ctx chunk (coalesced float4)
        {
            const float4* src = (const float4*)(ctx + (((size_t)b * T_ + t0) * D_));
            float4* dst = (float4*)(&ctx_s[0][0]);
            #pragma unroll
            for (int i = 0; i < (TC * D_ / 4) / 256; ++i)
                dst[tid + 256 * i] = src[tid + 256 * i];
        }
        // phi: UT*TC = 256 values, 1 per thread
        {
            int uu = tid >> 5;           // 2 distinct per wave -> LDS broadcast
            int tl = tid & 31;
            float tf = (float)(t0 + tl);
            float ph = 0.f;
            #pragma unroll
            for (int k = 0; k < K_; ++k) {
                float d = k_s[uu][k] - tf;
                float x = b_s[uu][k] * d * d;
                ph += a_s[uu][k] * __expf(-x);
            }
            phi_s[uu][tl] = ph * mask[(size_t)b * T_ + t0 + tl];
        }
        __syncthreads();
        // acc += phi * ctx   (phi hoisted 4-wide)
        for (int tl4 = 0; tl4 < TC / 4; ++tl4) {
            float4 ph4 = *(const float4*)(&phi_s[u_l][4 * tl4]);
            #pragma unroll
            for (int qq = 0; qq < 4; ++qq) {
                float ph = (qq == 0) ? ph4.x : (qq == 1) ? ph4.y : (qq == 2) ? ph4.z : ph4.w;
                float4 c0 = ((const float4*)(&ctx_s[4 * tl4 + qq][0]))[g];
                acc[0] += ph * c0.x; acc[1] += ph * c0.y;
                acc[2] += ph * c0.z; acc[3] += ph * c0.w;
            }
        }
    }

    float* orow = out + ((size_t)b * U_ + u0 + u_l) * D_;
    *(float4*)(orow + 4 * g) = make_float4(acc[0], acc[1], acc[2], acc[3]);
}

extern "C" void kernel_launch(void* const* d_in, const int* in_sizes, int n_in,
                              void* d_out, int out_size, void* d_ws, size_t ws_size,
                              hipStream_t stream) {
    const float* h_t  = (const float*)d_in[0];
    const float* ctx  = (const float*)d_in[1];
    const float* mask = (const float*)d_in[2];
    const float* W    = (const float*)d_in[3];
    const float* bias = (const float*)d_in[4];
    float* out = (float*)d_out;

    const size_t NPARAM = (size_t)B_ * U_ * K_;       // 40960
    float* alpha = (float*)d_ws;
    float* beta  = alpha + NPARAM;
    float* L     = beta + NPARAM;
    float* T     = L + NPARAM;                        // B*NTILES*K = 5120

    prep_kernel<<<dim3(512), dim3(512), 0, stream>>>(h_t, W, bias, alpha, beta, L, T);
    attend_kernel<<<dim3(512), dim3(256), 0, stream>>>(alpha, beta, L, T, ctx, mask, out);
}